// Round 11
// baseline (840.186 us; speedup 1.0000x reference)
//
#include <hip/hip_runtime.h>
#include <cstddef>

// ---------------------------------------------------------------------------
// Encoder, round 14: T4 counted-vmcnt tap-group pipeline + pool merge.
//  - conv_mfma group loop: raw s_barrier pair + counted s_waitcnt vmcnt(PF)
//    (PF = this wave's next-group loads in flight) — no vmcnt(0) drain in the
//    steady loop; B loads stay outstanding across the barrier (T4/m218).
//    Chunk boundaries keep full __syncthreads. FUSEIN ds_writes drained once
//    per chunk via lgkmcnt(0).
//  - poolf x2 merged into pool23 (m2+m3+counts in one dispatch).
//  - Tiles and fusions as round 13 (conv3b core otherwise untouched).
// ---------------------------------------------------------------------------

#define EPSV 1e-5f

typedef _Float16 f16x4 __attribute__((ext_vector_type(4)));
typedef _Float16 f16x8 __attribute__((ext_vector_type(8)));
typedef float f32x4 __attribute__((ext_vector_type(4)));

template <int KC> struct FragSel;
template <> struct FragSel<32> { using T = f16x8; };
template <> struct FragSel<16> { using T = f16x4; };

__device__ __forceinline__ f32x4 mfma16(f16x8 a, f16x8 b, f32x4 c) {
    return __builtin_amdgcn_mfma_f32_16x16x32_f16(a, b, c, 0, 0, 0);
}
__device__ __forceinline__ f32x4 mfma16(f16x4 a, f16x4 b, f32x4 c) {
    return __builtin_amdgcn_mfma_f32_16x16x16f16(a, b, c, 0, 0, 0);
}

// async global->LDS, 16B per lane; LDS dest = wave-uniform base + lane*16
__device__ __forceinline__ void gld16(const void* g, void* l) {
    __builtin_amdgcn_global_load_lds(
        (const __attribute__((address_space(1))) unsigned int*)g,
        (__attribute__((address_space(3))) unsigned int*)l, 16, 0, 0);
}

// self-inverse byte-offset swizzle: XOR 16B-chunk bits [4:6] with bits [7:9]
__device__ __forceinline__ int swz(int b) { return b ^ ((b >> 3) & 0x70); }

// ---------------- merged m2+m3 pooling (counts fused) ----------------
// block = one 8x8x4 m2-tile; grid 512 = 4 batch x 4 tw x 4 th x 8 td
__global__ __launch_bounds__(256) void pool23_kernel(const float* __restrict__ m1,
                                                     float* __restrict__ m2,
                                                     float* __restrict__ m3,
                                                     float* __restrict__ cnt2,
                                                     float* __restrict__ cnt3,
                                                     float* __restrict__ cnt3b) {
    int bid = blockIdx.x;
    int tw4 = bid & 3, th4 = (bid >> 2) & 3, td8 = (bid >> 4) & 7, b = bid >> 7;
    int tid = threadIdx.x;
    int lw = tid & 7, lh = (tid >> 3) & 7, ld = tid >> 6;       // 8x8x4
    int wo = tw4 * 8 + lw, ho = th4 * 8 + lh, dd = td8 * 4 + ld;  // m2 coords (32^3)
    float mx = 0.f;
#pragma unroll
    for (int dz = 0; dz < 2; ++dz)
#pragma unroll
        for (int hy = 0; hy < 2; ++hy)
#pragma unroll
            for (int wx = 0; wx < 2; ++wx) {
                size_t idx = ((size_t)((b * 64 + 2 * dd + dz) * 64 + 2 * ho + hy)) * 64
                             + 2 * wo + wx;
                mx = fmaxf(mx, m1[idx]);
            }
    m2[((size_t)((b * 32 + dd) * 32 + ho)) * 32 + wo] = mx;

    __shared__ float red[256];
    __shared__ float red3[32];
    red[tid] = mx;
    __syncthreads();
    // m3 gather: one thread per even (lw,lh,ld)
    if (((tid & 1) | ((tid >> 3) & 1) | ((tid >> 6) & 1)) == 0) {
        float v = red[tid];
        v = fmaxf(v, red[tid ^ 1]);
        v = fmaxf(v, red[tid ^ 8]);
        v = fmaxf(v, red[tid ^ 9]);
        v = fmaxf(v, red[tid ^ 64]);
        v = fmaxf(v, red[tid ^ 65]);
        v = fmaxf(v, red[tid ^ 72]);
        v = fmaxf(v, red[tid ^ 73]);
        int w3 = wo >> 1, h3 = ho >> 1, d3 = dd >> 1;
        m3[((size_t)((b * 16 + d3) * 16 + h3)) * 16 + w3] = v;
        int i32 = (lw >> 1) + 4 * (lh >> 1) + 16 * (ld >> 1);
        red3[i32] = v;
    }
    __syncthreads();
    // m2 sum tree
    for (int st = 128; st > 0; st >>= 1) {
        if (tid < st) red[tid] += red[tid + st];
        __syncthreads();
    }
    if (tid < 16) red3[tid] += red3[tid + 16];
    __syncthreads();
    if (tid < 8) red3[tid] += red3[tid + 8];
    __syncthreads();
    if (tid == 0) {
        float s3 = red3[0] + red3[1] + red3[2] + red3[3] + red3[4] + red3[5] + red3[6] + red3[7];
        atomicAdd(cnt2, red[0]);
        atomicAdd(cnt3, s3);
        atomicAdd(&cnt3b[b], s3);
    }
}

// ---------------- merged weight transform (LDS transpose, coalesced) -------
__global__ __launch_bounds__(256) void wtrans_all(
    const float* __restrict__ w1b, const float* __restrict__ w2a,
    const float* __restrict__ w2b, const float* __restrict__ w3a,
    const float* __restrict__ w3b,
    _Float16* __restrict__ o1b, _Float16* __restrict__ o2a,
    _Float16* __restrict__ o2b, _Float16* __restrict__ o3a,
    _Float16* __restrict__ o3b) {
    __shared__ float tile[32][33];
    int bid = blockIdx.x;
    const float* W; _Float16* O; int CIN, COUT, rel, TCO;
    if (bid < 27)        { W = w1b; O = o1b; CIN = 16;  COUT = 16;  rel = bid;        TCO = 1; }
    else if (bid < 81)   { W = w2a; O = o2a; CIN = 16;  COUT = 64;  rel = bid - 27;   TCO = 2; }
    else if (bid < 189)  { W = w2b; O = o2b; CIN = 64;  COUT = 64;  rel = bid - 81;   TCO = 2; }
    else if (bid < 1053) { W = w3a; O = o3a; CIN = 64;  COUT = 512; rel = bid - 189;  TCO = 16; }
    else                 { W = w3b; O = o3b; CIN = 512; COUT = 512; rel = bid - 1053; TCO = 16; }
    int TCI = (CIN + 31) >> 5;
    int per_t = TCI * TCO;
    int t = rel / per_t;
    int rr = rel - t * per_t;
    int tci = rr / TCO, tco = rr - tci * TCO;
    int ci0 = tci * 32, co0 = tco * 32;
    int tid = threadIdx.x;
    int c32 = tid & 31, r8 = tid >> 5;
#pragma unroll
    for (int j = 0; j < 4; ++j) {
        int ci = ci0 + j * 8 + r8, co = co0 + c32;
        if (ci < CIN && co < COUT)
            tile[j * 8 + r8][c32] = W[((size_t)t * CIN + ci) * COUT + co];
    }
    __syncthreads();
#pragma unroll
    for (int j = 0; j < 4; ++j) {
        int co = co0 + j * 8 + r8, ci = ci0 + c32;
        if (co < COUT && ci < CIN)
            O[((size_t)t * COUT + co) * CIN + ci] = (_Float16)tile[c32][j * 8 + r8];
    }
}

// ---------------- conv1a: Cin=1, Cout=16, stride 2 + fused pool0 + stats ---
__global__ __launch_bounds__(256) void conv1a_kernel(const float* __restrict__ x,
                                                     const int* __restrict__ mask,
                                                     const float* __restrict__ w,
                                                     float* __restrict__ m1,
                                                     _Float16* __restrict__ out,
                                                     float* __restrict__ stats,
                                                     float* __restrict__ cnt_total) {
    int voxel = blockIdx.x * 256 + threadIdx.x;  // 4 * 64^3
    int wo = voxel & 63, ho = (voxel >> 6) & 63, dd = (voxel >> 12) & 63, b = voxel >> 18;

    // fused pool0: OR of the 2x2x2 children (always in-bounds)
    int any = 0;
#pragma unroll
    for (int dz = 0; dz < 2; ++dz)
#pragma unroll
        for (int hy = 0; hy < 2; ++hy)
#pragma unroll
            for (int wx = 0; wx < 2; ++wx) {
                size_t idx = ((size_t)((b * 128 + 2 * dd + dz) * 128 + 2 * ho + hy)) * 128
                             + 2 * wo + wx;
                any |= mask[idx];
            }
    float mv = any ? 1.f : 0.f;
    m1[voxel] = mv;

    float acc[16];
#pragma unroll
    for (int i = 0; i < 16; ++i) acc[i] = 0.f;
    for (int kd = 0; kd < 3; ++kd) {
        int id = 2 * dd + kd - 1;
        if ((unsigned)id >= 128u) continue;
        for (int kh = 0; kh < 3; ++kh) {
            int ih = 2 * ho + kh - 1;
            if ((unsigned)ih >= 128u) continue;
            for (int kw = 0; kw < 3; ++kw) {
                int iw = 2 * wo + kw - 1;
                if ((unsigned)iw >= 128u) continue;
                size_t idx = ((size_t)((b * 128 + id) * 128 + ih)) * 128 + iw;
                float xv = x[idx] * (float)mask[idx];
                const float* wp = w + ((kd * 3 + kh) * 3 + kw) * 16;
#pragma unroll
                for (int co = 0; co < 16; ++co) acc[co] = fmaf(xv, wp[co], acc[co]);
            }
        }
    }
    _Float16* op = out + (size_t)voxel * 16;
    __shared__ float red[256 * 32];
    __shared__ float redm[256];
#pragma unroll
    for (int co = 0; co < 16; ++co) {
        float v = acc[co] * mv;
        op[co] = (_Float16)v;
        red[threadIdx.x * 32 + co] = v;
        red[threadIdx.x * 32 + 16 + co] = v * v;
    }
    redm[threadIdx.x] = mv;
    __syncthreads();
    for (int st = 128; st > 0; st >>= 1) {
        if (threadIdx.x < st) {
#pragma unroll
            for (int k = 0; k < 32; ++k)
                red[threadIdx.x * 32 + k] += red[(threadIdx.x + st) * 32 + k];
            redm[threadIdx.x] += redm[threadIdx.x + st];
        }
        __syncthreads();
    }
    if (threadIdx.x < 32) {
        float* sb = stats + (blockIdx.x & 7) * 32;
        atomicAdd(&sb[threadIdx.x], red[threadIdx.x]);
    }
    if (threadIdx.x == 32) atomicAdd(cnt_total, redm[0]);
}

// ---------------- unified MFMA implicit-GEMM conv ----------------
// Round-13 core with T4 counted-vmcnt tap-group pipeline.
template <int CIN, int COUT, int NTILE, int STRIDE, int NIN, int NOUT,
          int TW, int LTW, int TH, int LTH, int TD, int WM, int MINW, int TAPG,
          bool STATS, bool FUSEIN>
__global__ __launch_bounds__(256, MINW) void conv_mfma(const _Float16* __restrict__ in,
                                                       const _Float16* __restrict__ wt,
                                                       const float* __restrict__ mout,
                                                       _Float16* __restrict__ out,
                                                       const _Float16* __restrict__ zbuf,
                                                       float* __restrict__ stats,
                                                       const float* __restrict__ min_,
                                                       const float* __restrict__ statsi,
                                                       const float* __restrict__ cnti,
                                                       const float* __restrict__ gin,
                                                       const float* __restrict__ bin) {
    constexpr int M = TW * TH * TD;
    constexpr int KC = (CIN >= 32) ? 32 : 16;
    constexpr int KB = KC * 2;                 // bytes per voxel per K-chunk
    constexpr int LKB = (KC >= 32) ? 6 : 5;    // log2(KB)
    constexpr int HW_ = (TW - 1) * STRIDE + 3;
    constexpr int HH_ = (TH - 1) * STRIDE + 3;
    constexpr int HD_ = (TD - 1) * STRIDE + 3;
    constexpr int HV = HW_ * HH_ * HD_;
    constexpr int LPV = KB / 16;               // 16B chunks per voxel (4 or 2)
    constexpr int VPI = 64 / LPV;              // voxels per stage inst
    constexpr int NIH = (HV + VPI - 1) / VPI;
    constexpr int HVP = NIH * VPI;
    constexpr int WN = 4 / WM;
    constexpr int WMT = M / WM;
    constexpr int WNT = NTILE / WN;
    constexpr int NAF = WMT / 16;
    constexpr int NBF = WNT / 16;
    constexpr int NBLK = COUT / NTILE;
    constexpr int NTW = NOUT / TW, NTH = NOUT / TH, NTD = NOUT / TD;
    constexpr int NUMM = 4 * NTW * NTH * NTD;
    constexpr int BI = (NTILE * KB + 1023) / 1024;  // B stage insts per tap
    constexpr int NG = 27 / TAPG;                   // tap groups (27 % TAPG == 0)
    constexpr int BTAP = NTILE * KB;                // bytes per B tap tile
    static_assert(!FUSEIN || CIN == KC, "FUSEIN requires single K-chunk");

    using Frag = typename FragSel<KC>::T;

    __shared__ _Float16 halo[HVP * KC];
    __shared__ _Float16 bbuf[2 * TAPG * NTILE * KC];
    __shared__ float cfs[FUSEIN ? 2 * CIN : 2];

    // XCD-chunked block swizzle (all grids are multiples of 8)
    int cpx = gridDim.x >> 3;
    int bid = (blockIdx.x & 7) * cpx + (blockIdx.x >> 3);

    int nblk = (NBLK > 1) ? bid / NUMM : 0;
    int mblk = (NBLK > 1) ? bid % NUMM : bid;
    int tw = mblk % NTW;
    int th = (mblk / NTW) % NTH;
    int td = (mblk / (NTW * NTH)) % NTD;
    int b = mblk / (NTW * NTH * NTD);
    int d0 = td * TD * STRIDE - 1, h0 = th * TH * STRIDE - 1, w0 = tw * TW * STRIDE - 1;

    int tid = threadIdx.x;
    int wv = tid >> 6, lane = tid & 63, m16 = lane & 15, quad = lane >> 4;
    int wm_ = wv % WM, wn_ = wv / WM;
    int qb = quad * (KB / 4);   // quad's 16B(8B) chunk byte offset within voxel

    // per-wave gld16 count per tap-group (wave-uniform): 0, TAPG, or 2*TAPG
    const int nissue = ((wv < BI) ? 1 : 0) + ((wv + 4 < BI) ? 1 : 0);

    if constexpr (FUSEIN) {
        float cn = *cnti;
        for (int c = tid; c < CIN; c += 256) {
            float s = 0.f, q = 0.f;
#pragma unroll
            for (int k = 0; k < 8; ++k) {
                s += statsi[k * 2 * CIN + c];
                q += statsi[k * 2 * CIN + CIN + c];
            }
            float mean = s / cn;
            float var = q / cn - mean * mean;
            float sc = rsqrtf(var + EPSV) * gin[c];
            cfs[c] = sc;
            cfs[CIN + c] = bin[c] - mean * sc;
        }
    }

    // A fragment hoisted byte bases: swz input = abase_b[r] + tapv*KB
    int abase_b[NAF];
#pragma unroll
    for (int r = 0; r < NAF; ++r) {
        int vloc = wm_ * WMT + r * 16 + m16;
        int vw = vloc & (TW - 1), vh = (vloc >> LTW) & (TH - 1), vd = vloc >> (LTW + LTH);
        int avox = ((vd * STRIDE) * HH_ + vh * STRIDE) * HW_ + vw * STRIDE;
        abase_b[r] = avox * KB + qb;
    }
    // B fragment swizzled byte offsets (constant; relative to tap-slot base)
    int bofsw[NBF];
#pragma unroll
    for (int f = 0; f < NBF; ++f)
        bofsw[f] = swz((wn_ * WNT + f * 16 + m16) * KB + qb);

    // precomputed per-lane B stage source offsets (tap-invariant)
    int bsrc[2];
    bool bok[2];
#pragma unroll
    for (int k = 0; k < 2; ++k) {
        int i = wv + 4 * k;
        int S = i * 1024 + lane * 16;
        int Bq = swz(S);
        int row = Bq >> LKB;
        int cb = Bq & (KB - 1);
        bsrc[k] = row * CIN + (cb >> 1);
        bok[k] = (i < BI) && ((BTAP % 1024 == 0) || (row < NTILE));
    }

    f32x4 acc[NAF][NBF];
#pragma unroll
    for (int r = 0; r < NAF; ++r)
#pragma unroll
        for (int f = 0; f < NBF; ++f) acc[r][f] = (f32x4){0.f, 0.f, 0.f, 0.f};

    // stage halo: inst i fills LDS bytes [i*1024, +1024) linearly; lane's
    // source is the sigma-inverse of its slot (coalesced 64B segments).
    // FUSEIN: global->reg->BN/ELU/mask->ds_write; else global_load_lds.
    auto stage_halo = [&](int c0) {
        for (int i = wv; i < NIH; i += 4) {
            int S = i * 1024 + lane * 16;
            int Bq = swz(S);
            int hv = Bq >> LKB;
            int cb = Bq & (KB - 1);   // chunk byte offset within voxel
            int hw = hv % HW_;
            int t2 = hv / HW_;
            int hh = t2 % HH_;
            int hd = t2 / HH_;
            int d = d0 + hd, h = h0 + hh, w = w0 + hw;
            bool ok = (hv < HV) && ((unsigned)d < (unsigned)NIN) &&
                      ((unsigned)h < (unsigned)NIN) && ((unsigned)w < (unsigned)NIN);
            if constexpr (FUSEIN) {
                f16x8 o = (f16x8){0, 0, 0, 0, 0, 0, 0, 0};
                if (ok) {
                    size_t gvox = ((size_t)(((b * NIN + d) * NIN + h) * NIN + w));
                    f16x8 xv = *(const f16x8*)(in + gvox * CIN + (cb >> 1));
                    float mv = min_[gvox];
                    int cc = cb >> 1;
#pragma unroll
                    for (int k = 0; k < 8; ++k) {
                        float xh = (float)xv[k] * cfs[cc + k] + cfs[CIN + cc + k];
                        float e = xh > 0.f ? xh : expm1f(xh);
                        o[k] = (_Float16)(e * mv);
                    }
                }
                *(f16x8*)((char*)halo + S) = o;
            } else {
                const _Float16* g =
                    ok ? in + ((size_t)(((b * NIN + d) * NIN + h) * NIN + w)) * CIN + c0
                             + (cb >> 1)
                       : zbuf;
                gld16(g, (char*)halo + i * 1024);
            }
        }
    };

    // stage one B tap into slot jslot (0..2*TAPG-1)
    auto stage_B = [&](int tap, int jslot, int c0) {
        const _Float16* wb = wt + (size_t)tap * (COUT * CIN) + (size_t)nblk * NTILE * CIN + c0;
#pragma unroll
        for (int k = 0; k < 2; ++k) {
            if (bok[k])
                gld16(wb + bsrc[k], (char*)bbuf + (size_t)jslot * BTAP + (wv + 4 * k) * 1024);
        }
    };

    for (int c0 = 0; c0 < CIN; c0 += KC) {
        __syncthreads();   // chunk boundary: full drain, prev reads done
        stage_halo(c0);
        if constexpr (FUSEIN) asm volatile("s_waitcnt lgkmcnt(0)" ::: "memory");
#pragma unroll
        for (int j = 0; j < TAPG; ++j) stage_B(j, j, c0);

        for (int g = 0; g < NG; ++g) {
            // barrier 1: all waves done computing g-1 -> buf (g+1)&1 is free
            asm volatile("s_barrier" ::: "memory");
            if (g + 1 < NG) {
                int tb2 = (g + 1) * TAPG;
                int js = ((g + 1) & 1) * TAPG;
#pragma unroll
                for (int j = 0; j < TAPG; ++j) stage_B(tb2 + j, js + j, c0);
                // drain my group-g loads, leave group-(g+1)'s in flight
                if (nissue == 2)
                    asm volatile("s_waitcnt vmcnt(%0)" :: "i"(2 * TAPG) : "memory");
                else if (nissue == 1)
                    asm volatile("s_waitcnt vmcnt(%0)" :: "i"(TAPG) : "memory");
                else
                    asm volatile("s_waitcnt vmcnt(0)" ::: "memory");
            } else {
                asm volatile("s_waitcnt vmcnt(0)" ::: "memory");
            }
            // barrier 2: all waves' group-g data visible in LDS
            asm volatile("s_barrier" ::: "memory");

            int tb = g * TAPG;
            int kd = tb / 9, rr = tb - kd * 9, kh = rr / 3, kw = rr - kh * 3;
            int tvb = ((kd * HH_ + kh) * HW_ + kw) * KB;
            const char* bp = (const char*)bbuf + (size_t)((g & 1) * TAPG) * BTAP;
            __builtin_amdgcn_s_setprio(1);
#pragma unroll
            for (int j = 0; j < TAPG; ++j) {
                Frag a[NAF], bb[NBF];
#pragma unroll
                for (int r = 0; r < NAF; ++r)
                    a[r] = *(const Frag*)((const char*)halo + swz(abase_b[r] + tvb + j * KB));
#pragma unroll
                for (int f = 0; f < NBF; ++f)
                    bb[f] = *(const Frag*)(bp + (size_t)j * BTAP + bofsw[f]);
#pragma unroll
                for (int r = 0; r < NAF; ++r)
#pragma unroll
                    for (int f = 0; f < NBF; ++f) acc[r][f] = mfma16(a[r], bb[f], acc[r][f]);
            }
            __builtin_amdgcn_s_setprio(0);
        }
    }

    // epilogue: C/D col = m16 (cout), row = quad*4 + j (voxel within frag)
    int n0 = nblk * NTILE + wn_ * WNT + m16;
    float sv[NBF], qv[NBF];
    if constexpr (STATS) {
#pragma unroll
        for (int f = 0; f < NBF; ++f) { sv[f] = 0.f; qv[f] = 0.f; }
    }
#pragma unroll
    for (int r = 0; r < NAF; ++r) {
#pragma unroll
        for (int j = 0; j < 4; ++j) {
            int vloc = wm_ * WMT + r * 16 + quad * 4 + j;
            int vw = vloc & (TW - 1), vh = (vloc >> LTW) & (TH - 1), vd = vloc >> (LTW + LTH);
            int od = td * TD + vd, oh = th * TH + vh, ow = tw * TW + vw;
            size_t gvox = ((size_t)((b * NOUT + od) * NOUT + oh)) * NOUT + ow;
            float mv = mout[gvox];
            _Float16* op = out + gvox * COUT + n0;
#pragma unroll
            for (int f = 0; f < NBF; ++f) {
                float val = acc[r][f][j] * mv;
                op[f * 16] = (_Float16)val;
                if constexpr (STATS) { sv[f] += val; qv[f] += val * val; }
            }
        }
    }
    if constexpr (STATS) {
        float* sb = stats + (blockIdx.x & 7) * (2 * COUT);
#pragma unroll
        for (int f = 0; f < NBF; ++f) {
            float s = sv[f], q = qv[f];
            s += __shfl_xor(s, 16);
            s += __shfl_xor(s, 32);
            q += __shfl_xor(q, 16);
            q += __shfl_xor(q, 32);
            if (lane < 16) {
                int c = n0 + f * 16;
                atomicAdd(&sb[c], s);
                atomicAdd(&sb[COUT + c], q);
            }
        }
    }
}

// ---------------- BN apply + ELU + mask, coef computed in-kernel ----------
template <int C, int LOGC>
__global__ __launch_bounds__(256) void bn_apply2(_Float16* __restrict__ x,
                                                 const float* __restrict__ m,
                                                 const float* __restrict__ stats,
                                                 const float* __restrict__ cntp,
                                                 const float* __restrict__ gamma,
                                                 const float* __restrict__ beta, long n) {
    __shared__ float cf[2 * C];
    float cn = *cntp;
    for (int c = threadIdx.x; c < C; c += 256) {
        float s = 0.f, q = 0.f;
#pragma unroll
        for (int k = 0; k < 8; ++k) {
            s += stats[k * 2 * C + c];
            q += stats[k * 2 * C + C + c];
        }
        float mean = s / cn;
        float var = q / cn - mean * mean;
        float sc = rsqrtf(var + EPSV) * gamma[c];
        cf[c] = sc;
        cf[C + c] = beta[c] - mean * sc;
    }
    __syncthreads();
    long stride = (long)gridDim.x * 2048;
    for (long i8 = ((long)blockIdx.x * 256 + threadIdx.x) * 8; i8 < n; i8 += stride) {
        int c = (int)(i8 & (C - 1));
        long v = i8 >> LOGC;
        f16x8 xv = *(const f16x8*)(x + i8);
        float mv = m[v];
        f16x8 o;
#pragma unroll
        for (int k = 0; k < 8; ++k) {
            float xh = (float)xv[k] * cf[c + k] + cf[C + c + k];
            float e = xh > 0.f ? xh : expm1f(xh);
            o[k] = (_Float16)(e * mv);
        }
        *(f16x8*)(x + i8) = o;
    }
}

// ---------------- global masked mean pool (inline coef + BN+ELU) ----------
__global__ __launch_bounds__(256) void gpool_kernel(const _Float16* __restrict__ h,
                                                    const float* __restrict__ m3,
                                                    const float* __restrict__ stats,
                                                    const float* __restrict__ cntp,
                                                    const float* __restrict__ gamma,
                                                    const float* __restrict__ beta,
                                                    float* __restrict__ pooled) {
    __shared__ float cf[1024];
    float cn = *cntp;
    for (int c = threadIdx.x; c < 512; c += 256) {
        float s = 0.f, q = 0.f;
#pragma unroll
        for (int k = 0; k < 8; ++k) {
            s += stats[k * 1024 + c];
            q += stats[k * 1024 + 512 + c];
        }
        float mean = s / cn;
        float var = q / cn - mean * mean;
        float sc = rsqrtf(var + EPSV) * gamma[c];
        cf[c] = sc;
        cf[512 + c] = beta[c] - mean * sc;
    }
    __syncthreads();
    int b = blockIdx.x >> 6, seg = blockIdx.x & 63;  // 64 segments of 64 voxels
    int ch = (threadIdx.x & 63) * 8;
    int v0 = threadIdx.x >> 6;
    float scl[8], shf[8];
#pragma unroll
    for (int k = 0; k < 8; ++k) {
        scl[k] = cf[ch + k];
        shf[k] = cf[512 + ch + k];
    }
    float s[8];
#pragma unroll
    for (int k = 0; k < 8; ++k) s[k] = 0.f;
    for (int v = v0; v < 64; v += 4) {
        int vox = b * 4096 + seg * 64 + v;
        float mv = m3[vox];
        f16x8 xv = *(const f16x8*)(h + (size_t)vox * 512 + ch);
#pragma unroll
        for (int k = 0; k < 8; ++k) {
            float xh = (float)xv[k] * scl[k] + shf[k];
            float e = xh > 0.f ? xh : expm1f(xh);
            s[k] += e * mv;
        }
    }
#pragma unroll
    for (int k = 0; k < 8; ++k) atomicAdd(&pooled[b * 512 + ch + k], s[k]);
}

// ---------------- heads ----------------
__global__ __launch_bounds__(256) void head_kernel(const float* __restrict__ pooled,
                                                   const float* __restrict__ cntb,
                                                   const float* __restrict__ wm,
                                                   const float* __restrict__ bm,
                                                   const float* __restrict__ wv,
                                                   const float* __restrict__ bv,
                                                   float* __restrict__ out) {
    int t = blockIdx.x * 256 + threadIdx.x;  // 4096
    int which = t >> 11;
    int b = (t >> 9) & 3;
    int j = t & 511;
    const float* W = which ? wv : wm;
    float bias = which ? bv[j] : bm[j];
    const float* p = pooled + b * 512;
    float s = 0.f;
    for (int c = 0; c < 512; ++c) s = fmaf(p[c], W[c * 512 + j], s);
    out[t] = s / cntb[b] + bias;
}

// ---------------------------------------------------------------------------
extern "C" void kernel_launch(void* const* d_in, const int* in_sizes, int n_in,
                              void* d_out, int out_size, void* d_ws, size_t ws_size,
                              hipStream_t stream) {
    const float* x   = (const float*)d_in[0];
    const int* mask  = (const int*)d_in[1];
    const float* w1a = (const float*)d_in[2];
    const float* g1a = (const float*)d_in[3];
    const float* b1a = (const float*)d_in[4];
    const float* w1b = (const float*)d_in[5];
    const float* g1b = (const float*)d_in[6];
    const float* b1b = (const float*)d_in[7];
    const float* w2a = (const float*)d_in[8];
    const float* g2a = (const float*)d_in[9];
    const float* b2a = (const float*)d_in[10];
    const float* w2b = (const float*)d_in[11];
    const float* g2b = (const float*)d_in[12];
    const float* b2b = (const float*)d_in[13];
    const float* w3a = (const float*)d_in[14];
    const float* g3a = (const float*)d_in[15];
    const float* b3a = (const float*)d_in[16];
    const float* w3b = (const float*)d_in[17];
    const float* g3b = (const float*)d_in[18];
    const float* b3b = (const float*)d_in[19];
    const float* wm  = (const float*)d_in[20];
    const float* bm  = (const float*)d_in[21];
    const float* wv  = (const float*)d_in[22];
    const float* bv  = (const float*)d_in[23];
    float* out = (float*)d_out;

    char* ws = (char*)d_ws;
    _Float16* A  = (_Float16*)(ws + 0);            // 32 MiB activations ping
    _Float16* Bb = (_Float16*)(ws + 33554432);     // 32 MiB activations pong
    _Float16* w1bh = (_Float16*)(ws + 67108864);   // 13,824 B
    _Float16* w2ah = (_Float16*)(ws + 67125248);   // 55,296 B
    _Float16* w2bh = (_Float16*)(ws + 67182592);   // 221,184 B
    _Float16* w3ah = (_Float16*)(ws + 67403776);   // 1,769,472 B
    _Float16* w3bh = (_Float16*)(ws + 69173248);   // 14,155,776 B
    float* m1 = (float*)(ws + 83329024);           // 4 MiB
    float* m2 = (float*)(ws + 87523328);           // 512 KiB
    float* m3 = (float*)(ws + 88047616);           // 64 KiB
    float* counts = (float*)(ws + 88113152);       // 64 B
    float* stats  = (float*)(ws + 88113216);       // 6 x 8192 floats = 192 KiB
    float* pooled = (float*)(ws + 88309824);       // 8 KiB
    _Float16* zbuf = (_Float16*)(ws + 88318016);   // 256 B zeros

    float* sL0 = stats;                 // h1a stats (C=16)
    float* sL1 = stats + 1 * 8192;      // h1b stats (C=16)
    float* sL2 = stats + 2 * 8192;      // h2a (C=64, 8 slots)
    float* sL3 = stats + 3 * 8192;      // h2b
    float* sL4 = stats + 4 * 8192;      // h3a (C=512, 8 slots)
    float* sL5 = stats + 5 * 8192;      // h3b

    _Float16* h1a = A;
    _Float16* h1b = Bb;
    _Float16* h2a = A;
    _Float16* h2b = Bb;
    _Float16* h3a = A;
    _Float16* h3b = Bb;

    // one upfront clear: counts + stats + pooled + zbuf (contiguous)
    hipMemsetAsync(counts, 0, 64 + 196608 + 8192 + 256, stream);

    // merged weight transforms (independent of everything else)
    wtrans_all<<<7965, 256, 0, stream>>>(w1b, w2a, w2b, w3a, w3b,
                                         w1bh, w2ah, w2bh, w3ah, w3bh);

    // ---- block 1 (conv1a emits m1 + count0 + stats) ----
    conv1a_kernel<<<4096, 256, 0, stream>>>(x, mask, w1a, m1, h1a, sL0, counts + 0);
    pool23_kernel<<<512, 256, 0, stream>>>(m1, m2, m3, counts + 1, counts + 2, counts + 4);

    // conv1b: 8x8x8 tile, fused input BN (h1a stats), output stats sL1
    conv_mfma<16, 16, 16, 1, 64, 64, 8, 3, 8, 3, 8, 4, 4, 3, true, true>
        <<<2048, 256, 0, stream>>>(h1a, w1bh, m1, h1b, zbuf, sL1,
                                   m1, sL0, counts + 0, g1a, b1a);

    // ---- block 2 ----
    // conv2a: 8x4x4 tile, fused input BN (h1b stats), output stats sL2
    conv_mfma<16, 64, 64, 2, 64, 32, 8, 3, 4, 2, 4, 2, 2, 3, true, true>
        <<<1024, 256, 0, stream>>>(h1b, w2ah, m2, h2a, zbuf, sL2,
                                   m1, sL1, counts + 0, g1b, b1b);
    bn_apply2<64, 6><<<1024, 256, 0, stream>>>(h2a, m2, sL2, counts + 1, g2a, b2a, 8388608L);

    // conv2b: 8x8x4 tile (NAF=8, 16 MFMA/tap)
    conv_mfma<64, 64, 64, 1, 32, 32, 8, 3, 8, 3, 4, 2, 2, 3, true, false>
        <<<512, 256, 0, stream>>>(h2a, w2bh, m2, h2b, zbuf, sL3,
                                  nullptr, nullptr, nullptr, nullptr, nullptr);
    bn_apply2<64, 6><<<1024, 256, 0, stream>>>(h2b, m2, sL3, counts + 1, g2b, b2b, 8388608L);

    // ---- block 3 ----
    // conv3a: NTILE=128, TAPG=1 (8 MFMA/tap, halo restage 4x)
    conv_mfma<64, 512, 128, 2, 32, 16, 4, 2, 4, 2, 4, 2, 2, 1, true, false>
        <<<1024, 256, 0, stream>>>(h2b, w3ah, m3, h3a, zbuf, sL4,
                                   nullptr, nullptr, nullptr, nullptr, nullptr);
    bn_apply2<512, 9><<<512, 256, 0, stream>>>(h3a, m3, sL4, counts + 2, g3a, b3a, 8388608L);

    conv_mfma<512, 512, 128, 1, 16, 16, 8, 3, 4, 2, 4, 2, 2, 3, true, false>
        <<<512, 256, 0, stream>>>(h3a, w3bh, m3, h3b, zbuf, sL5,
                                  nullptr, nullptr, nullptr, nullptr, nullptr);

    // ---- pool (BN inline) + heads ----
    gpool_kernel<<<256, 256, 0, stream>>>(h3b, m3, sL5, counts + 2, g3b, b3b, pooled);
    head_kernel<<<16, 256, 0, stream>>>(pooled, counts + 4, wm, bm, wv, bv, out);
}

// Round 12
// 805.129 us; speedup vs baseline: 1.0435x; 1.0435x over previous
//
#include <hip/hip_runtime.h>
#include <cstddef>

// ---------------------------------------------------------------------------
// Encoder, round 15: T4 reverted (neutral, m139 repeat) + cheap cuts.
//  - conv_mfma loop: round-13 __syncthreads structure (validated).
//  - ELU via __expf-1 (one v_exp_f32) instead of libm expm1f.
//  - wtrans_all merged into conv1a launch (block-range split, -1 dispatch).
//  - conv2b input-BN fused (FUSEIN generalized to multi-chunk; 4.7x recompute
//    is below the round-9 break-even; conv3a/3b stay unfused at 23x/45x).
//  - pool23 kept. 15 -> 12 dispatches.
// ---------------------------------------------------------------------------

#define EPSV 1e-5f

typedef _Float16 f16x4 __attribute__((ext_vector_type(4)));
typedef _Float16 f16x8 __attribute__((ext_vector_type(8)));
typedef float f32x4 __attribute__((ext_vector_type(4)));

template <int KC> struct FragSel;
template <> struct FragSel<32> { using T = f16x8; };
template <> struct FragSel<16> { using T = f16x4; };

__device__ __forceinline__ f32x4 mfma16(f16x8 a, f16x8 b, f32x4 c) {
    return __builtin_amdgcn_mfma_f32_16x16x32_f16(a, b, c, 0, 0, 0);
}
__device__ __forceinline__ f32x4 mfma16(f16x4 a, f16x4 b, f32x4 c) {
    return __builtin_amdgcn_mfma_f32_16x16x16f16(a, b, c, 0, 0, 0);
}

// async global->LDS, 16B per lane; LDS dest = wave-uniform base + lane*16
__device__ __forceinline__ void gld16(const void* g, void* l) {
    __builtin_amdgcn_global_load_lds(
        (const __attribute__((address_space(1))) unsigned int*)g,
        (__attribute__((address_space(3))) unsigned int*)l, 16, 0, 0);
}

// self-inverse byte-offset swizzle: XOR 16B-chunk bits [4:6] with bits [7:9]
__device__ __forceinline__ int swz(int b) { return b ^ ((b >> 3) & 0x70); }

// fast ELU negative branch: exp(x)-1 via v_exp_f32 (x<=0 here, error << 2e-3)
__device__ __forceinline__ float elu_(float x) { return x > 0.f ? x : __expf(x) - 1.f; }

// ---------------- merged m2+m3 pooling (counts fused) ----------------
// block = one 8x8x4 m2-tile; grid 512 = 4 batch x 4 tw x 4 th x 8 td
__global__ __launch_bounds__(256) void pool23_kernel(const float* __restrict__ m1,
                                                     float* __restrict__ m2,
                                                     float* __restrict__ m3,
                                                     float* __restrict__ cnt2,
                                                     float* __restrict__ cnt3,
                                                     float* __restrict__ cnt3b) {
    int bid = blockIdx.x;
    int tw4 = bid & 3, th4 = (bid >> 2) & 3, td8 = (bid >> 4) & 7, b = bid >> 7;
    int tid = threadIdx.x;
    int lw = tid & 7, lh = (tid >> 3) & 7, ld = tid >> 6;       // 8x8x4
    int wo = tw4 * 8 + lw, ho = th4 * 8 + lh, dd = td8 * 4 + ld;  // m2 coords (32^3)
    float mx = 0.f;
#pragma unroll
    for (int dz = 0; dz < 2; ++dz)
#pragma unroll
        for (int hy = 0; hy < 2; ++hy)
#pragma unroll
            for (int wx = 0; wx < 2; ++wx) {
                size_t idx = ((size_t)((b * 64 + 2 * dd + dz) * 64 + 2 * ho + hy)) * 64
                             + 2 * wo + wx;
                mx = fmaxf(mx, m1[idx]);
            }
    m2[((size_t)((b * 32 + dd) * 32 + ho)) * 32 + wo] = mx;

    __shared__ float red[256];
    __shared__ float red3[32];
    red[tid] = mx;
    __syncthreads();
    // m3 gather: one thread per even (lw,lh,ld)
    if (((tid & 1) | ((tid >> 3) & 1) | ((tid >> 6) & 1)) == 0) {
        float v = red[tid];
        v = fmaxf(v, red[tid ^ 1]);
        v = fmaxf(v, red[tid ^ 8]);
        v = fmaxf(v, red[tid ^ 9]);
        v = fmaxf(v, red[tid ^ 64]);
        v = fmaxf(v, red[tid ^ 65]);
        v = fmaxf(v, red[tid ^ 72]);
        v = fmaxf(v, red[tid ^ 73]);
        int w3 = wo >> 1, h3 = ho >> 1, d3 = dd >> 1;
        m3[((size_t)((b * 16 + d3) * 16 + h3)) * 16 + w3] = v;
        int i32 = (lw >> 1) + 4 * (lh >> 1) + 16 * (ld >> 1);
        red3[i32] = v;
    }
    __syncthreads();
    // m2 sum tree
    for (int st = 128; st > 0; st >>= 1) {
        if (tid < st) red[tid] += red[tid + st];
        __syncthreads();
    }
    if (tid < 16) red3[tid] += red3[tid + 16];
    __syncthreads();
    if (tid < 8) red3[tid] += red3[tid + 8];
    __syncthreads();
    if (tid == 0) {
        float s3 = red3[0] + red3[1] + red3[2] + red3[3] + red3[4] + red3[5] + red3[6] + red3[7];
        atomicAdd(cnt2, red[0]);
        atomicAdd(cnt3, s3);
        atomicAdd(&cnt3b[b], s3);
    }
}

// ---------------- prep: conv1a (+pool0+stats+count) || wtrans_all ----------
// blocks [0,4096): conv1a; blocks [4096,12061): weight transforms.
__global__ __launch_bounds__(256) void prep_kernel(
    const float* __restrict__ x, const int* __restrict__ mask,
    const float* __restrict__ w1a, float* __restrict__ m1,
    _Float16* __restrict__ out, float* __restrict__ stats,
    float* __restrict__ cnt_total,
    const float* __restrict__ w1b, const float* __restrict__ w2a,
    const float* __restrict__ w2b, const float* __restrict__ w3a,
    const float* __restrict__ w3b,
    _Float16* __restrict__ o1b, _Float16* __restrict__ o2a,
    _Float16* __restrict__ o2b, _Float16* __restrict__ o3a,
    _Float16* __restrict__ o3b) {
    if (blockIdx.x >= 4096) {
        // ---- weight transform branch (LDS transpose, coalesced) ----
        __shared__ float tile[32][33];
        int bid = blockIdx.x - 4096;
        const float* W; _Float16* O; int CIN, COUT, rel, TCO;
        if (bid < 27)        { W = w1b; O = o1b; CIN = 16;  COUT = 16;  rel = bid;        TCO = 1; }
        else if (bid < 81)   { W = w2a; O = o2a; CIN = 16;  COUT = 64;  rel = bid - 27;   TCO = 2; }
        else if (bid < 189)  { W = w2b; O = o2b; CIN = 64;  COUT = 64;  rel = bid - 81;   TCO = 2; }
        else if (bid < 1053) { W = w3a; O = o3a; CIN = 64;  COUT = 512; rel = bid - 189;  TCO = 16; }
        else                 { W = w3b; O = o3b; CIN = 512; COUT = 512; rel = bid - 1053; TCO = 16; }
        int TCI = (CIN + 31) >> 5;
        int per_t = TCI * TCO;
        int t = rel / per_t;
        int rr = rel - t * per_t;
        int tci = rr / TCO, tco = rr - tci * TCO;
        int ci0 = tci * 32, co0 = tco * 32;
        int tid = threadIdx.x;
        int c32 = tid & 31, r8 = tid >> 5;
#pragma unroll
        for (int j = 0; j < 4; ++j) {
            int ci = ci0 + j * 8 + r8, co = co0 + c32;
            if (ci < CIN && co < COUT)
                tile[j * 8 + r8][c32] = W[((size_t)t * CIN + ci) * COUT + co];
        }
        __syncthreads();
#pragma unroll
        for (int j = 0; j < 4; ++j) {
            int co = co0 + j * 8 + r8, ci = ci0 + c32;
            if (co < COUT && ci < CIN)
                O[((size_t)t * COUT + co) * CIN + ci] = (_Float16)tile[c32][j * 8 + r8];
        }
        return;
    }
    // ---- conv1a branch ----
    int voxel = blockIdx.x * 256 + threadIdx.x;  // 4 * 64^3
    int wo = voxel & 63, ho = (voxel >> 6) & 63, dd = (voxel >> 12) & 63, b = voxel >> 18;

    int any = 0;
#pragma unroll
    for (int dz = 0; dz < 2; ++dz)
#pragma unroll
        for (int hy = 0; hy < 2; ++hy)
#pragma unroll
            for (int wx = 0; wx < 2; ++wx) {
                size_t idx = ((size_t)((b * 128 + 2 * dd + dz) * 128 + 2 * ho + hy)) * 128
                             + 2 * wo + wx;
                any |= mask[idx];
            }
    float mv = any ? 1.f : 0.f;
    m1[voxel] = mv;

    float acc[16];
#pragma unroll
    for (int i = 0; i < 16; ++i) acc[i] = 0.f;
    for (int kd = 0; kd < 3; ++kd) {
        int id = 2 * dd + kd - 1;
        if ((unsigned)id >= 128u) continue;
        for (int kh = 0; kh < 3; ++kh) {
            int ih = 2 * ho + kh - 1;
            if ((unsigned)ih >= 128u) continue;
            for (int kw = 0; kw < 3; ++kw) {
                int iw = 2 * wo + kw - 1;
                if ((unsigned)iw >= 128u) continue;
                size_t idx = ((size_t)((b * 128 + id) * 128 + ih)) * 128 + iw;
                float xv = x[idx] * (float)mask[idx];
                const float* wp = w1a + ((kd * 3 + kh) * 3 + kw) * 16;
#pragma unroll
                for (int co = 0; co < 16; ++co) acc[co] = fmaf(xv, wp[co], acc[co]);
            }
        }
    }
    _Float16* op = out + (size_t)voxel * 16;
    __shared__ float red[256 * 32];
    __shared__ float redm[256];
#pragma unroll
    for (int co = 0; co < 16; ++co) {
        float v = acc[co] * mv;
        op[co] = (_Float16)v;
        red[threadIdx.x * 32 + co] = v;
        red[threadIdx.x * 32 + 16 + co] = v * v;
    }
    redm[threadIdx.x] = mv;
    __syncthreads();
    for (int st = 128; st > 0; st >>= 1) {
        if (threadIdx.x < st) {
#pragma unroll
            for (int k = 0; k < 32; ++k)
                red[threadIdx.x * 32 + k] += red[(threadIdx.x + st) * 32 + k];
            redm[threadIdx.x] += redm[threadIdx.x + st];
        }
        __syncthreads();
    }
    if (threadIdx.x < 32) {
        float* sb = stats + (blockIdx.x & 7) * 32;
        atomicAdd(&sb[threadIdx.x], red[threadIdx.x]);
    }
    if (threadIdx.x == 32) atomicAdd(cnt_total, redm[0]);
}

// ---------------- unified MFMA implicit-GEMM conv ----------------
// Round-13 core; FUSEIN (any CIN): reg-staged halo with input BN+ELU+mask
// applied in flight per K-chunk, coefs from producer stats.
template <int CIN, int COUT, int NTILE, int STRIDE, int NIN, int NOUT,
          int TW, int LTW, int TH, int LTH, int TD, int WM, int MINW, int TAPG,
          bool STATS, bool FUSEIN>
__global__ __launch_bounds__(256, MINW) void conv_mfma(const _Float16* __restrict__ in,
                                                       const _Float16* __restrict__ wt,
                                                       const float* __restrict__ mout,
                                                       _Float16* __restrict__ out,
                                                       const _Float16* __restrict__ zbuf,
                                                       float* __restrict__ stats,
                                                       const float* __restrict__ min_,
                                                       const float* __restrict__ statsi,
                                                       const float* __restrict__ cnti,
                                                       const float* __restrict__ gin,
                                                       const float* __restrict__ bin) {
    constexpr int M = TW * TH * TD;
    constexpr int KC = (CIN >= 32) ? 32 : 16;
    constexpr int KB = KC * 2;                 // bytes per voxel per K-chunk
    constexpr int LKB = (KC >= 32) ? 6 : 5;    // log2(KB)
    constexpr int HW_ = (TW - 1) * STRIDE + 3;
    constexpr int HH_ = (TH - 1) * STRIDE + 3;
    constexpr int HD_ = (TD - 1) * STRIDE + 3;
    constexpr int HV = HW_ * HH_ * HD_;
    constexpr int LPV = KB / 16;               // 16B chunks per voxel (4 or 2)
    constexpr int VPI = 64 / LPV;              // voxels per stage inst
    constexpr int NIH = (HV + VPI - 1) / VPI;
    constexpr int HVP = NIH * VPI;
    constexpr int WN = 4 / WM;
    constexpr int WMT = M / WM;
    constexpr int WNT = NTILE / WN;
    constexpr int NAF = WMT / 16;
    constexpr int NBF = WNT / 16;
    constexpr int NBLK = COUT / NTILE;
    constexpr int NTW = NOUT / TW, NTH = NOUT / TH, NTD = NOUT / TD;
    constexpr int NUMM = 4 * NTW * NTH * NTD;
    constexpr int BI = (NTILE * KB + 1023) / 1024;  // B stage insts per tap
    constexpr int NG = 27 / TAPG;                   // tap groups (27 % TAPG == 0)
    constexpr int BTAP = NTILE * KB;                // bytes per B tap tile

    using Frag = typename FragSel<KC>::T;

    __shared__ _Float16 halo[HVP * KC];
    __shared__ _Float16 bbuf[2 * TAPG * NTILE * KC];
    __shared__ float cfs[FUSEIN ? 2 * CIN : 2];

    // XCD-chunked block swizzle (all grids are multiples of 8)
    int cpx = gridDim.x >> 3;
    int bid = (blockIdx.x & 7) * cpx + (blockIdx.x >> 3);

    int nblk = (NBLK > 1) ? bid / NUMM : 0;
    int mblk = (NBLK > 1) ? bid % NUMM : bid;
    int tw = mblk % NTW;
    int th = (mblk / NTW) % NTH;
    int td = (mblk / (NTW * NTH)) % NTD;
    int b = mblk / (NTW * NTH * NTD);
    int d0 = td * TD * STRIDE - 1, h0 = th * TH * STRIDE - 1, w0 = tw * TW * STRIDE - 1;

    int tid = threadIdx.x;
    int wv = tid >> 6, lane = tid & 63, m16 = lane & 15, quad = lane >> 4;
    int wm_ = wv % WM, wn_ = wv / WM;
    int qb = quad * (KB / 4);   // quad's 16B(8B) chunk byte offset within voxel

    if constexpr (FUSEIN) {
        float cn = *cnti;
        for (int c = tid; c < CIN; c += 256) {
            float s = 0.f, q = 0.f;
#pragma unroll
            for (int k = 0; k < 8; ++k) {
                s += statsi[k * 2 * CIN + c];
                q += statsi[k * 2 * CIN + CIN + c];
            }
            float mean = s / cn;
            float var = q / cn - mean * mean;
            float sc = rsqrtf(var + EPSV) * gin[c];
            cfs[c] = sc;
            cfs[CIN + c] = bin[c] - mean * sc;
        }
    }

    // A fragment hoisted byte bases: swz input = abase_b[r] + tapv*KB
    int abase_b[NAF];
#pragma unroll
    for (int r = 0; r < NAF; ++r) {
        int vloc = wm_ * WMT + r * 16 + m16;
        int vw = vloc & (TW - 1), vh = (vloc >> LTW) & (TH - 1), vd = vloc >> (LTW + LTH);
        int avox = ((vd * STRIDE) * HH_ + vh * STRIDE) * HW_ + vw * STRIDE;
        abase_b[r] = avox * KB + qb;
    }
    // B fragment swizzled byte offsets (constant; relative to tap-slot base)
    int bofsw[NBF];
#pragma unroll
    for (int f = 0; f < NBF; ++f)
        bofsw[f] = swz((wn_ * WNT + f * 16 + m16) * KB + qb);

    // precomputed per-lane B stage source offsets (tap-invariant)
    int bsrc[2];
    bool bok[2];
#pragma unroll
    for (int k = 0; k < 2; ++k) {
        int i = wv + 4 * k;
        int S = i * 1024 + lane * 16;
        int Bq = swz(S);
        int row = Bq >> LKB;
        int cb = Bq & (KB - 1);
        bsrc[k] = row * CIN + (cb >> 1);
        bok[k] = (i < BI) && ((BTAP % 1024 == 0) || (row < NTILE));
    }

    f32x4 acc[NAF][NBF];
#pragma unroll
    for (int r = 0; r < NAF; ++r)
#pragma unroll
        for (int f = 0; f < NBF; ++f) acc[r][f] = (f32x4){0.f, 0.f, 0.f, 0.f};

    // stage halo: inst i fills LDS bytes [i*1024, +1024) linearly; lane's
    // source is the sigma-inverse of its slot (coalesced 64B segments).
    // FUSEIN: global->reg->BN/ELU/mask->ds_write; else global_load_lds.
    auto stage_halo = [&](int c0) {
        for (int i = wv; i < NIH; i += 4) {
            int S = i * 1024 + lane * 16;
            int Bq = swz(S);
            int hv = Bq >> LKB;
            int cb = Bq & (KB - 1);   // chunk byte offset within voxel
            int hw = hv % HW_;
            int t2 = hv / HW_;
            int hh = t2 % HH_;
            int hd = t2 / HH_;
            int d = d0 + hd, h = h0 + hh, w = w0 + hw;
            bool ok = (hv < HV) && ((unsigned)d < (unsigned)NIN) &&
                      ((unsigned)h < (unsigned)NIN) && ((unsigned)w < (unsigned)NIN);
            if constexpr (FUSEIN) {
                f16x8 o = (f16x8){0, 0, 0, 0, 0, 0, 0, 0};
                if (ok) {
                    size_t gvox = ((size_t)(((b * NIN + d) * NIN + h) * NIN + w));
                    f16x8 xv = *(const f16x8*)(in + gvox * CIN + c0 + (cb >> 1));
                    float mv = min_[gvox];
                    int cc = c0 + (cb >> 1);
#pragma unroll
                    for (int k = 0; k < 8; ++k) {
                        float xh = (float)xv[k] * cfs[cc + k] + cfs[CIN + cc + k];
                        o[k] = (_Float16)(elu_(xh) * mv);
                    }
                }
                *(f16x8*)((char*)halo + S) = o;
            } else {
                const _Float16* g =
                    ok ? in + ((size_t)(((b * NIN + d) * NIN + h) * NIN + w)) * CIN + c0
                             + (cb >> 1)
                       : zbuf;
                gld16(g, (char*)halo + i * 1024);
            }
        }
    };

    // stage one B tap into slot jslot (0..2*TAPG-1)
    auto stage_B = [&](int tap, int jslot, int c0) {
        const _Float16* wb = wt + (size_t)tap * (COUT * CIN) + (size_t)nblk * NTILE * CIN + c0;
#pragma unroll
        for (int k = 0; k < 2; ++k) {
            if (bok[k])
                gld16(wb + bsrc[k], (char*)bbuf + (size_t)jslot * BTAP + (wv + 4 * k) * 1024);
        }
    };

    for (int c0 = 0; c0 < CIN; c0 += KC) {
        __syncthreads();   // prev reads done; cfs visible (first iter)
        stage_halo(c0);
#pragma unroll
        for (int j = 0; j < TAPG; ++j) stage_B(j, j, c0);

        for (int g = 0; g < NG; ++g) {
            __syncthreads();   // staged data for group g visible
            if (g + 1 < NG) {
                int tb2 = (g + 1) * TAPG;
                int js = ((g + 1) & 1) * TAPG;
#pragma unroll
                for (int j = 0; j < TAPG; ++j) stage_B(tb2 + j, js + j, c0);
            }
            int tb = g * TAPG;
            int kd = tb / 9, rr = tb - kd * 9, kh = rr / 3, kw = rr - kh * 3;
            int tvb = ((kd * HH_ + kh) * HW_ + kw) * KB;
            const char* bp = (const char*)bbuf + (size_t)((g & 1) * TAPG) * BTAP;
            __builtin_amdgcn_s_setprio(1);
#pragma unroll
            for (int j = 0; j < TAPG; ++j) {
                Frag a[NAF], bb[NBF];
#pragma unroll
                for (int r = 0; r < NAF; ++r)
                    a[r] = *(const Frag*)((const char*)halo + swz(abase_b[r] + tvb + j * KB));
#pragma unroll
                for (int f = 0; f < NBF; ++f)
                    bb[f] = *(const Frag*)(bp + (size_t)j * BTAP + bofsw[f]);
#pragma unroll
                for (int r = 0; r < NAF; ++r)
#pragma unroll
                    for (int f = 0; f < NBF; ++f) acc[r][f] = mfma16(a[r], bb[f], acc[r][f]);
            }
            __builtin_amdgcn_s_setprio(0);
        }
    }

    // epilogue: C/D col = m16 (cout), row = quad*4 + j (voxel within frag)
    int n0 = nblk * NTILE + wn_ * WNT + m16;
    float sv[NBF], qv[NBF];
    if constexpr (STATS) {
#pragma unroll
        for (int f = 0; f < NBF; ++f) { sv[f] = 0.f; qv[f] = 0.f; }
    }
#pragma unroll
    for (int r = 0; r < NAF; ++r) {
#pragma unroll
        for (int j = 0; j < 4; ++j) {
            int vloc = wm_ * WMT + r * 16 + quad * 4 + j;
            int vw = vloc & (TW - 1), vh = (vloc >> LTW) & (TH - 1), vd = vloc >> (LTW + LTH);
            int od = td * TD + vd, oh = th * TH + vh, ow = tw * TW + vw;
            size_t gvox = ((size_t)((b * NOUT + od) * NOUT + oh)) * NOUT + ow;
            float mv = mout[gvox];
            _Float16* op = out + gvox * COUT + n0;
#pragma unroll
            for (int f = 0; f < NBF; ++f) {
                float val = acc[r][f][j] * mv;
                op[f * 16] = (_Float16)val;
                if constexpr (STATS) { sv[f] += val; qv[f] += val * val; }
            }
        }
    }
    if constexpr (STATS) {
        float* sb = stats + (blockIdx.x & 7) * (2 * COUT);
#pragma unroll
        for (int f = 0; f < NBF; ++f) {
            float s = sv[f], q = qv[f];
            s += __shfl_xor(s, 16);
            s += __shfl_xor(s, 32);
            q += __shfl_xor(q, 16);
            q += __shfl_xor(q, 32);
            if (lane < 16) {
                int c = n0 + f * 16;
                atomicAdd(&sb[c], s);
                atomicAdd(&sb[COUT + c], q);
            }
        }
    }
}

// ---------------- BN apply + ELU + mask, coef computed in-kernel ----------
template <int C, int LOGC>
__global__ __launch_bounds__(256) void bn_apply2(_Float16* __restrict__ x,
                                                 const float* __restrict__ m,
                                                 const float* __restrict__ stats,
                                                 const float* __restrict__ cntp,
                                                 const float* __restrict__ gamma,
                                                 const float* __restrict__ beta, long n) {
    __shared__ float cf[2 * C];
    float cn = *cntp;
    for (int c = threadIdx.x; c < C; c += 256) {
        float s = 0.f, q = 0.f;
#pragma unroll
        for (int k = 0; k < 8; ++k) {
            s += stats[k * 2 * C + c];
            q += stats[k * 2 * C + C + c];
        }
        float mean = s / cn;
        float var = q / cn - mean * mean;
        float sc = rsqrtf(var + EPSV) * gamma[c];
        cf[c] = sc;
        cf[C + c] = beta[c] - mean * sc;
    }
    __syncthreads();
    long stride = (long)gridDim.x * 2048;
    for (long i8 = ((long)blockIdx.x * 256 + threadIdx.x) * 8; i8 < n; i8 += stride) {
        int c = (int)(i8 & (C - 1));
        long v = i8 >> LOGC;
        f16x8 xv = *(const f16x8*)(x + i8);
        float mv = m[v];
        f16x8 o;
#pragma unroll
        for (int k = 0; k < 8; ++k) {
            float xh = (float)xv[k] * cf[c + k] + cf[C + c + k];
            o[k] = (_Float16)(elu_(xh) * mv);
        }
        *(f16x8*)(x + i8) = o;
    }
}

// ---------------- global masked mean pool (inline coef + BN+ELU) ----------
__global__ __launch_bounds__(256) void gpool_kernel(const _Float16* __restrict__ h,
                                                    const float* __restrict__ m3,
                                                    const float* __restrict__ stats,
                                                    const float* __restrict__ cntp,
                                                    const float* __restrict__ gamma,
                                                    const float* __restrict__ beta,
                                                    float* __restrict__ pooled) {
    __shared__ float cf[1024];
    float cn = *cntp;
    for (int c = threadIdx.x; c < 512; c += 256) {
        float s = 0.f, q = 0.f;
#pragma unroll
        for (int k = 0; k < 8; ++k) {
            s += stats[k * 1024 + c];
            q += stats[k * 1024 + 512 + c];
        }
        float mean = s / cn;
        float var = q / cn - mean * mean;
        float sc = rsqrtf(var + EPSV) * gamma[c];
        cf[c] = sc;
        cf[512 + c] = beta[c] - mean * sc;
    }
    __syncthreads();
    int b = blockIdx.x >> 6, seg = blockIdx.x & 63;  // 64 segments of 64 voxels
    int ch = (threadIdx.x & 63) * 8;
    int v0 = threadIdx.x >> 6;
    float scl[8], shf[8];
#pragma unroll
    for (int k = 0; k < 8; ++k) {
        scl[k] = cf[ch + k];
        shf[k] = cf[512 + ch + k];
    }
    float s[8];
#pragma unroll
    for (int k = 0; k < 8; ++k) s[k] = 0.f;
    for (int v = v0; v < 64; v += 4) {
        int vox = b * 4096 + seg * 64 + v;
        float mv = m3[vox];
        f16x8 xv = *(const f16x8*)(h + (size_t)vox * 512 + ch);
#pragma unroll
        for (int k = 0; k < 8; ++k) {
            float xh = (float)xv[k] * scl[k] + shf[k];
            s[k] += elu_(xh) * mv;
        }
    }
#pragma unroll
    for (int k = 0; k < 8; ++k) atomicAdd(&pooled[b * 512 + ch + k], s[k]);
}

// ---------------- heads ----------------
__global__ __launch_bounds__(256) void head_kernel(const float* __restrict__ pooled,
                                                   const float* __restrict__ cntb,
                                                   const float* __restrict__ wm,
                                                   const float* __restrict__ bm,
                                                   const float* __restrict__ wv,
                                                   const float* __restrict__ bv,
                                                   float* __restrict__ out) {
    int t = blockIdx.x * 256 + threadIdx.x;  // 4096
    int which = t >> 11;
    int b = (t >> 9) & 3;
    int j = t & 511;
    const float* W = which ? wv : wm;
    float bias = which ? bv[j] : bm[j];
    const float* p = pooled + b * 512;
    float s = 0.f;
    for (int c = 0; c < 512; ++c) s = fmaf(p[c], W[c * 512 + j], s);
    out[t] = s / cntb[b] + bias;
}

// ---------------------------------------------------------------------------
extern "C" void kernel_launch(void* const* d_in, const int* in_sizes, int n_in,
                              void* d_out, int out_size, void* d_ws, size_t ws_size,
                              hipStream_t stream) {
    const float* x   = (const float*)d_in[0];
    const int* mask  = (const int*)d_in[1];
    const float* w1a = (const float*)d_in[2];
    const float* g1a = (const float*)d_in[3];
    const float* b1a = (const float*)d_in[4];
    const float* w1b = (const float*)d_in[5];
    const float* g1b = (const float*)d_in[6];
    const float* b1b = (const float*)d_in[7];
    const float* w2a = (const float*)d_in[8];
    const float* g2a = (const float*)d_in[9];
    const float* b2a = (const float*)d_in[10];
    const float* w2b = (const float*)d_in[11];
    const float* g2b = (const float*)d_in[12];
    const float* b2b = (const float*)d_in[13];
    const float* w3a = (const float*)d_in[14];
    const float* g3a = (const float*)d_in[15];
    const float* b3a = (const float*)d_in[16];
    const float* w3b = (const float*)d_in[17];
    const float* g3b = (const float*)d_in[18];
    const float* b3b = (const float*)d_in[19];
    const float* wm  = (const float*)d_in[20];
    const float* bm  = (const float*)d_in[21];
    const float* wv  = (const float*)d_in[22];
    const float* bv  = (const float*)d_in[23];
    float* out = (float*)d_out;

    char* ws = (char*)d_ws;
    _Float16* A  = (_Float16*)(ws + 0);            // 32 MiB activations ping
    _Float16* Bb = (_Float16*)(ws + 33554432);     // 32 MiB activations pong
    _Float16* w1bh = (_Float16*)(ws + 67108864);   // 13,824 B
    _Float16* w2ah = (_Float16*)(ws + 67125248);   // 55,296 B
    _Float16* w2bh = (_Float16*)(ws + 67182592);   // 221,184 B
    _Float16* w3ah = (_Float16*)(ws + 67403776);   // 1,769,472 B
    _Float16* w3bh = (_Float16*)(ws + 69173248);   // 14,155,776 B
    float* m1 = (float*)(ws + 83329024);           // 4 MiB
    float* m2 = (float*)(ws + 87523328);           // 512 KiB
    float* m3 = (float*)(ws + 88047616);           // 64 KiB
    float* counts = (float*)(ws + 88113152);       // 64 B
    float* stats  = (float*)(ws + 88113216);       // 6 x 8192 floats = 192 KiB
    float* pooled = (float*)(ws + 88309824);       // 8 KiB
    _Float16* zbuf = (_Float16*)(ws + 88318016);   // 256 B zeros

    float* sL0 = stats;                 // h1a stats (C=16)
    float* sL1 = stats + 1 * 8192;      // h1b stats (C=16)
    float* sL2 = stats + 2 * 8192;      // h2a (C=64, 8 slots)
    float* sL3 = stats + 3 * 8192;      // h2b
    float* sL4 = stats + 4 * 8192;      // h3a (C=512, 8 slots)
    float* sL5 = stats + 5 * 8192;      // h3b

    _Float16* h1a = A;
    _Float16* h1b = Bb;
    _Float16* h2a = A;
    _Float16* h2b = Bb;
    _Float16* h3a = A;
    _Float16* h3b = Bb;

    // one upfront clear: counts + stats + pooled + zbuf (contiguous)
    hipMemsetAsync(counts, 0, 64 + 196608 + 8192 + 256, stream);

    // ---- prep: conv1a (m1 + count0 + stats) || all weight transforms ----
    prep_kernel<<<12061, 256, 0, stream>>>(x, mask, w1a, m1, h1a, sL0, counts + 0,
                                           w1b, w2a, w2b, w3a, w3b,
                                           w1bh, w2ah, w2bh, w3ah, w3bh);
    pool23_kernel<<<512, 256, 0, stream>>>(m1, m2, m3, counts + 1, counts + 2, counts + 4);

    // conv1b: 8x8x8 tile, fused input BN (h1a stats), output stats sL1
    conv_mfma<16, 16, 16, 1, 64, 64, 8, 3, 8, 3, 8, 4, 4, 3, true, true>
        <<<2048, 256, 0, stream>>>(h1a, w1bh, m1, h1b, zbuf, sL1,
                                   m1, sL0, counts + 0, g1a, b1a);

    // ---- block 2 ----
    // conv2a: 8x4x4 tile, fused input BN (h1b stats), output stats sL2
    conv_mfma<16, 64, 64, 2, 64, 32, 8, 3, 4, 2, 4, 2, 2, 3, true, true>
        <<<1024, 256, 0, stream>>>(h1b, w2ah, m2, h2a, zbuf, sL2,
                                   m1, sL1, counts + 0, g1b, b1b);

    // conv2b: 8x8x4 tile, fused input BN (h2a stats, 2 chunks x 2.34 overlap)
    conv_mfma<64, 64, 64, 1, 32, 32, 8, 3, 8, 3, 4, 2, 2, 3, true, true>
        <<<512, 256, 0, stream>>>(h2a, w2bh, m2, h2b, zbuf, sL3,
                                  m2, sL2, counts + 1, g2a, b2a);
    bn_apply2<64, 6><<<1024, 256, 0, stream>>>(h2b, m2, sL3, counts + 1, g2b, b2b, 8388608L);

    // ---- block 3 ----
    // conv3a: NTILE=128, TAPG=1 (8 MFMA/tap, halo restage 4x)
    conv_mfma<64, 512, 128, 2, 32, 16, 4, 2, 4, 2, 4, 2, 2, 1, true, false>
        <<<1024, 256, 0, stream>>>(h2b, w3ah, m3, h3a, zbuf, sL4,
                                   nullptr, nullptr, nullptr, nullptr, nullptr);
    bn_apply2<512, 9><<<512, 256, 0, stream>>>(h3a, m3, sL4, counts + 2, g3a, b3a, 8388608L);

    conv_mfma<512, 512, 128, 1, 16, 16, 8, 3, 4, 2, 4, 2, 2, 3, true, false>
        <<<512, 256, 0, stream>>>(h3a, w3bh, m3, h3b, zbuf, sL5,
                                  nullptr, nullptr, nullptr, nullptr, nullptr);

    // ---- pool (BN inline) + heads ----
    gpool_kernel<<<256, 256, 0, stream>>>(h3b, m3, sL5, counts + 2, g3b, b3b, pooled);
    head_kernel<<<16, 256, 0, stream>>>(pooled, counts + 4, wm, bm, wv, bv, out);
}